// Round 3
// baseline (694.456 us; speedup 1.0000x reference)
//
#include <hip/hip_runtime.h>
#include <math.h>

#define BB 16
#define SS 4096
#define HH 1024
#define SCH 64    // s-chunk for weighted-sum kernel

// d_ws layout (fast path):
//   [0, 256 KB)              : scores / attn probs, B*S fp32 (atomicAdd target)
//   [256 KB, 256 KB + 4 MB)  : W hi/lo bf16, chunk-ordered [ct(8)][kc(32)] x 16 KB
//   [+4 MB, +4 MB + 256 MB)  : x hi/lo bf16, chunk-ordered [b*32+rt][kc(32)] x 16 KB
// chunk (16 KB) internal: [plane(2)][rowblk(4)][kh(2)] x 1 KB, each 1 KB =
//   [khsel(2)][row(32)] x 16 B  ->  LDS offset = chunk*1024 + lane*16 exactly.

typedef __attribute__((ext_vector_type(8))) short bf16x8;
typedef __attribute__((ext_vector_type(16))) float f32x16;

__device__ __forceinline__ void gl_lds16(const void* g, void* l) {
  __builtin_amdgcn_global_load_lds(
      (const __attribute__((address_space(1))) void*)g,
      (__attribute__((address_space(3))) void*)l, 16, 0, 0);
}

// split 8 fp32 -> 8 bf16 hi (16 B) + 8 bf16 lo (16 B)
__device__ __forceinline__ void pack8(float4 a, float4 b, uint4& hp, uint4& lp) {
  float f[8] = {a.x, a.y, a.z, a.w, b.x, b.y, b.z, b.w};
  unsigned h[8], l[8];
#pragma unroll
  for (int i = 0; i < 8; ++i) {
    unsigned u = __float_as_uint(f[i]);
    h[i] = u >> 16;
    l[i] = __float_as_uint(f[i] - __uint_as_float(u & 0xffff0000u)) >> 16;
  }
  hp.x = h[0] | (h[1] << 16); hp.y = h[2] | (h[3] << 16);
  hp.z = h[4] | (h[5] << 16); hp.w = h[6] | (h[7] << 16);
  lp.x = l[0] | (l[1] << 16); lp.y = l[2] | (l[3] << 16);
  lp.z = l[4] | (l[5] << 16); lp.w = l[6] | (l[7] << 16);
}

// ---- W -> chunk-ordered hi/lo bf16 ----------------------------------------
__global__ __launch_bounds__(256) void conv_w_tiled(const float* __restrict__ W,
                                                    char* __restrict__ Bt) {
  int ct = blockIdx.x, kc = blockIdx.y;
  char* blk = Bt + (size_t)(ct * 32 + kc) * 16384;
  int tid = threadIdx.x;
#pragma unroll
  for (int i = 0; i < 2; ++i) {
    int oi = i * 256 + tid;
    int n = oi >> 2, koct = oi & 3;
    const float* src = W + (size_t)(ct * 128 + n) * HH + kc * 32 + koct * 8;
    float4 v0 = *(const float4*)src;
    float4 v1 = *(const float4*)(src + 4);
    uint4 hp, lp;
    pack8(v0, v1, hp, lp);
    int nb = n >> 5, nrow = n & 31, kh = koct >> 1, khs = koct & 1;
    int off = (((nb * 2 + kh) * 2 + khs) << 9) + nrow * 16;
    *(uint4*)(blk + off) = hp;
    *(uint4*)(blk + 8192 + off) = lp;   // plane=1 -> +8 KB
  }
}

// ---- x (valid row-tiles only) -> chunk-ordered hi/lo bf16 -----------------
__global__ __launch_bounds__(256) void conv_x_tiled(const float* __restrict__ x,
                                                    const int* __restrict__ lengths,
                                                    char* __restrict__ Ax) {
  int rt = blockIdx.x, b = blockIdx.y;
  if (rt * 128 >= lengths[b]) return;
  int tid = threadIdx.x;
  const float* xb = x + ((size_t)b * SS + rt * 128) * HH;
  char* tile0 = Ax + (size_t)(b * 32 + rt) * 32 * 16384;
#pragma unroll 4
  for (int i = 0; i < 64; ++i) {
    int oi = i * 256 + tid;
    int r = oi >> 7, koct = oi & 127;
    const float* src = xb + (size_t)r * HH + koct * 8;
    float4 v0 = *(const float4*)src;
    float4 v1 = *(const float4*)(src + 4);
    uint4 hp, lp;
    pack8(v0, v1, hp, lp);
    int kc = koct >> 2, ko = koct & 3;
    int rb = r >> 5, mrow = r & 31, kh = ko >> 1, khs = ko & 1;
    char* blk = tile0 + kc * 16384;
    int off = (((rb * 2 + kh) * 2 + khs) << 9) + mrow * 16;
    *(uint4*)(blk + off) = hp;
    *(uint4*)(blk + 8192 + off) = lp;
  }
}

// ---- fast scores GEMM: all staging via global_load_lds, zero-conflict LDS --
__global__ __launch_bounds__(256, 4) void scores_gemm_fast(
    const char* __restrict__ Ax, const int* __restrict__ lengths,
    const char* __restrict__ Bt, const float* __restrict__ bias,
    const float* __restrict__ key, float* __restrict__ scores) {
  int ct = blockIdx.x;
  int t = blockIdx.y;
  int b = t >> 5;
  int rt = t & 31;
  int s0 = rt * 128;
  if (s0 >= lengths[b]) return;

  __shared__ char lds[32768];
  int tid = threadIdx.x;
  int lane = tid & 63, w = tid >> 6;
  int wm = w & 1, wn = w >> 1;

  f32x16 acc[2][2];
#pragma unroll
  for (int mt = 0; mt < 2; ++mt)
#pragma unroll
    for (int nt = 0; nt < 2; ++nt)
#pragma unroll
      for (int i = 0; i < 16; ++i) acc[mt][nt][i] = 0.f;

  const char* Ag = Ax + (size_t)(b * 32 + rt) * 32 * 16384;
  const char* Bg = Bt + (size_t)ct * 32 * 16384;

  for (int kc = 0; kc < 32; ++kc) {
    const char* Ak = Ag + kc * 16384;
    const char* Bk = Bg + kc * 16384;
#pragma unroll
    for (int i = 0; i < 4; ++i) {
      int c = w * 4 + i;
      gl_lds16(Ak + c * 1024 + lane * 16, lds + c * 1024);
      gl_lds16(Bk + c * 1024 + lane * 16, lds + 16384 + c * 1024);
    }
    __syncthreads();   // drains vmcnt (lds-DMA)

#pragma unroll
    for (int kh = 0; kh < 2; ++kh) {
      bf16x8 ah[2], al[2], bh[2], bl[2];
#pragma unroll
      for (int mt = 0; mt < 2; ++mt) {
        ah[mt] = *(bf16x8*)(lds + (((wm * 2 + mt) * 2 + kh) << 10) + lane * 16);
        al[mt] = *(bf16x8*)(lds + 8192 + (((wm * 2 + mt) * 2 + kh) << 10) + lane * 16);
        bh[mt] = *(bf16x8*)(lds + 16384 + (((wn * 2 + mt) * 2 + kh) << 10) + lane * 16);
        bl[mt] = *(bf16x8*)(lds + 24576 + (((wn * 2 + mt) * 2 + kh) << 10) + lane * 16);
      }
#pragma unroll
      for (int mt = 0; mt < 2; ++mt)
#pragma unroll
        for (int nt = 0; nt < 2; ++nt) {
          acc[mt][nt] = __builtin_amdgcn_mfma_f32_32x32x16_bf16(
              ah[mt], bh[nt], acc[mt][nt], 0, 0, 0);
          acc[mt][nt] = __builtin_amdgcn_mfma_f32_32x32x16_bf16(
              ah[mt], bl[nt], acc[mt][nt], 0, 0, 0);
          acc[mt][nt] = __builtin_amdgcn_mfma_f32_32x32x16_bf16(
              al[mt], bh[nt], acc[mt][nt], 0, 0, 0);
        }
    }
    __syncthreads();
  }

  // epilogue: scores[row] += sum_o tanh(pre + bias[o]) * key[o]
  // C/D map (32x32): col = lane&31, row = (reg&3) + 8*(reg>>2) + 4*(lane>>5)
  int col = lane & 31;
  int rbase = (lane >> 5) * 4;
  float bo[2], ko[2];
#pragma unroll
  for (int nt = 0; nt < 2; ++nt) {
    int o = ct * 128 + wn * 64 + nt * 32 + col;
    bo[nt] = bias[o];
    ko[nt] = key[o];
  }
  float* srow = scores + (size_t)b * SS + s0;
#pragma unroll
  for (int mt = 0; mt < 2; ++mt) {
#pragma unroll
    for (int reg = 0; reg < 16; ++reg) {
      float sv = tanhf(acc[mt][0][reg] + bo[0]) * ko[0] +
                 tanhf(acc[mt][1][reg] + bo[1]) * ko[1];
#pragma unroll
      for (int off = 1; off < 32; off <<= 1) sv += __shfl_xor(sv, off);
      if (col == 0) {
        int row = wm * 64 + mt * 32 + (reg & 3) + 8 * (reg >> 2) + rbase;
        atomicAdd(srow + row, sv);
      }
    }
  }
}

// ================= fallback path (round-2 kernels, used if ws too small) ====
__global__ __launch_bounds__(256) void conv_w_flat(const float* __restrict__ W,
                                                   unsigned short* __restrict__ Bbuf) {
  int ct = blockIdx.x, kc = blockIdx.y;
  unsigned short* blk = Bbuf + (size_t)(ct * 32 + kc) * 8192;
  int tid = threadIdx.x;
#pragma unroll
  for (int it = 0; it < 16; ++it) {
    int flat = it * 256 + tid;
    int n = flat >> 5, kk = flat & 31;
    float f = W[(size_t)(ct * 128 + n) * HH + kc * 32 + kk];
    unsigned u = __float_as_uint(f);
    float hf = __uint_as_float(u & 0xffff0000u);
    blk[n * 32 + kk] = (unsigned short)(u >> 16);
    blk[4096 + n * 32 + kk] = (unsigned short)(__float_as_uint(f - hf) >> 16);
  }
}

__global__ __launch_bounds__(256, 2) void scores_gemm_split(
    const float* __restrict__ x, const int* __restrict__ lengths,
    const unsigned short* __restrict__ Bbuf, const float* __restrict__ bias,
    const float* __restrict__ key, float* __restrict__ scores) {
  int ct = blockIdx.x;
  int t = blockIdx.y;
  int b = t >> 5;
  int s0 = (t & 31) * 128;
  if (s0 >= lengths[b]) return;

  __shared__ char lds[32768];
  int tid = threadIdx.x;
  int lane = tid & 63, w = tid >> 6;
  int wm = w & 1, wn = w >> 1;

  f32x16 acc[2][2];
#pragma unroll
  for (int mt = 0; mt < 2; ++mt)
#pragma unroll
    for (int nt = 0; nt < 2; ++nt)
#pragma unroll
      for (int i = 0; i < 16; ++i) acc[mt][nt][i] = 0.f;

  const float* xb = x + ((size_t)b * SS + s0) * HH;
  const char* Bblk0 = (const char*)Bbuf + (size_t)ct * 32 * 16384;
  int ar = tid >> 3;
  int ak = (tid & 7) * 4;
  int mrow = lane & 31;
  int khsel = lane >> 5;
  char* aP = lds + (wm * 64 + mrow) * 64 + khsel * 16;
  char* bP = lds + 16384 + (wn * 64 + mrow) * 64 + khsel * 16;

  for (int kc = 0; kc < 32; ++kc) {
    const char* Bblk = Bblk0 + kc * 16384;
#pragma unroll
    for (int i = 0; i < 4; ++i) {
      int c = w * 4 + i;
      gl_lds16(Bblk + c * 1024 + lane * 16, lds + 16384 + c * 1024);
    }
#pragma unroll
    for (int it = 0; it < 4; ++it) {
      int r = ar + it * 32;
      float4 v = *(const float4*)(xb + (size_t)r * HH + kc * 32 + ak);
      unsigned u0 = __float_as_uint(v.x), u1 = __float_as_uint(v.y);
      unsigned u2 = __float_as_uint(v.z), u3 = __float_as_uint(v.w);
      float l0 = v.x - __uint_as_float(u0 & 0xffff0000u);
      float l1 = v.y - __uint_as_float(u1 & 0xffff0000u);
      float l2 = v.z - __uint_as_float(u2 & 0xffff0000u);
      float l3 = v.w - __uint_as_float(u3 & 0xffff0000u);
      uint2 hp, lp;
      hp.x = (u0 >> 16) | (u1 & 0xffff0000u);
      hp.y = (u2 >> 16) | (u3 & 0xffff0000u);
      lp.x = (__float_as_uint(l0) >> 16) | (__float_as_uint(l1) & 0xffff0000u);
      lp.y = (__float_as_uint(l2) >> 16) | (__float_as_uint(l3) & 0xffff0000u);
      *(uint2*)(lds + r * 64 + ak * 2) = hp;
      *(uint2*)(lds + 8192 + r * 64 + ak * 2) = lp;
    }
    __syncthreads();

#pragma unroll
    for (int kh = 0; kh < 2; ++kh) {
      bf16x8 ah[2], al[2], bh[2], bl[2];
#pragma unroll
      for (int mt = 0; mt < 2; ++mt) {
        ah[mt] = *(bf16x8*)(aP + mt * 2048 + kh * 32);
        al[mt] = *(bf16x8*)(aP + 8192 + mt * 2048 + kh * 32);
        bh[mt] = *(bf16x8*)(bP + mt * 2048 + kh * 32);
        bl[mt] = *(bf16x8*)(bP + 8192 + mt * 2048 + kh * 32);
      }
#pragma unroll
      for (int mt = 0; mt < 2; ++mt)
#pragma unroll
        for (int nt = 0; nt < 2; ++nt) {
          acc[mt][nt] = __builtin_amdgcn_mfma_f32_32x32x16_bf16(
              ah[mt], bh[nt], acc[mt][nt], 0, 0, 0);
          acc[mt][nt] = __builtin_amdgcn_mfma_f32_32x32x16_bf16(
              ah[mt], bl[nt], acc[mt][nt], 0, 0, 0);
          acc[mt][nt] = __builtin_amdgcn_mfma_f32_32x32x16_bf16(
              al[mt], bh[nt], acc[mt][nt], 0, 0, 0);
        }
    }
    __syncthreads();
  }

  int col = lane & 31;
  int rbase = (lane >> 5) * 4;
  float bo[2], ko[2];
#pragma unroll
  for (int nt = 0; nt < 2; ++nt) {
    int o = ct * 128 + wn * 64 + nt * 32 + col;
    bo[nt] = bias[o];
    ko[nt] = key[o];
  }
  float* srow = scores + (size_t)b * SS + s0;
#pragma unroll
  for (int mt = 0; mt < 2; ++mt) {
#pragma unroll
    for (int reg = 0; reg < 16; ++reg) {
      float sv = tanhf(acc[mt][0][reg] + bo[0]) * ko[0] +
                 tanhf(acc[mt][1][reg] + bo[1]) * ko[1];
#pragma unroll
      for (int off = 1; off < 32; off <<= 1) sv += __shfl_xor(sv, off);
      if (col == 0) {
        int row = wm * 64 + mt * 32 + (reg & 3) + 8 * (reg >> 2) + rbase;
        atomicAdd(srow + row, sv);
      }
    }
  }
}

// ---- masked softmax over s < L, in place -----------------------------------
__global__ __launch_bounds__(256) void softmax_kernel(float* __restrict__ sc,
                                                      const int* __restrict__ lengths) {
  int b = blockIdx.x;
  int L = lengths[b];
  float* p = sc + (size_t)b * SS;
  __shared__ float sred[34];
  int tid = threadIdx.x;

  float m = -3.0e38f;
  for (int s = tid; s < L; s += 256) m = fmaxf(m, p[s]);
  for (int off = 32; off > 0; off >>= 1) m = fmaxf(m, __shfl_down(m, off));
  if ((tid & 63) == 0) sred[tid >> 6] = m;
  __syncthreads();
  if (tid == 0) {
    float mm = sred[0];
    for (int w = 1; w < 4; ++w) mm = fmaxf(mm, sred[w]);
    sred[32] = mm;
  }
  __syncthreads();
  m = sred[32];

  float z = 0.f;
  for (int s = tid; s < L; s += 256) z += expf(p[s] - m);
  for (int off = 32; off > 0; off >>= 1) z += __shfl_down(z, off);
  if ((tid & 63) == 0) sred[tid >> 6] = z;
  __syncthreads();
  if (tid == 0) {
    float zz = 0.f;
    for (int w = 0; w < 4; ++w) zz += sred[w];
    sred[33] = zz;
  }
  __syncthreads();
  float inv = 1.f / sred[33];
  for (int s = tid; s < L; s += 256) p[s] = expf(p[s] - m) * inv;
}

// ---- out[b,h] = sum_{s<L} p[b,s] * x[b,s,h] --------------------------------
__global__ __launch_bounds__(256) void wsum_kernel(const float* __restrict__ x,
                                                   const float* __restrict__ p,
                                                   const int* __restrict__ lengths,
                                                   float* __restrict__ out) {
  int b = blockIdx.y;
  int L = lengths[b];
  int sbeg = blockIdx.x * SCH;
  if (sbeg >= L) return;
  int send = min(sbeg + SCH, L);
  int h = threadIdx.x * 4;
  const float* xb = x + (size_t)b * SS * HH;
  const float* pb = p + (size_t)b * SS;
  float4 acc = {0.f, 0.f, 0.f, 0.f};
#pragma unroll 4
  for (int s = sbeg; s < send; ++s) {
    float wgt = pb[s];
    float4 v = *(const float4*)(xb + (size_t)s * HH + h);
    acc.x = fmaf(wgt, v.x, acc.x);
    acc.y = fmaf(wgt, v.y, acc.y);
    acc.z = fmaf(wgt, v.z, acc.z);
    acc.w = fmaf(wgt, v.w, acc.w);
  }
  float* o = out + (size_t)b * HH + h;
  atomicAdd(o + 0, acc.x);
  atomicAdd(o + 1, acc.y);
  atomicAdd(o + 2, acc.z);
  atomicAdd(o + 3, acc.w);
}

extern "C" void kernel_launch(void* const* d_in, const int* in_sizes, int n_in,
                              void* d_out, int out_size, void* d_ws, size_t ws_size,
                              hipStream_t stream) {
  const float* x = (const float*)d_in[0];
  const int* lengths = (const int*)d_in[1];
  const float* W = (const float*)d_in[2];
  const float* bias = (const float*)d_in[3];
  const float* key = (const float*)d_in[4];
  float* out = (float*)d_out;

  float* scores = (float*)d_ws;                                   // 256 KB
  char* Bt = (char*)d_ws + 256 * 1024;                            // 4 MB
  char* Ax = Bt + (size_t)4 * 1024 * 1024;                        // 256 MB

  const size_t NEED = 256 * 1024 + (size_t)4 * 1024 * 1024 +
                      (size_t)16 * 32 * 32 * 16384;               // ~272.9 MB

  hipMemsetAsync(d_out, 0, (size_t)out_size * sizeof(float), stream);
  hipMemsetAsync(scores, 0, (size_t)BB * SS * sizeof(float), stream);

  if (ws_size >= NEED) {
    conv_w_tiled<<<dim3(8, 32), 256, 0, stream>>>(W, Bt);
    conv_x_tiled<<<dim3(32, BB), 256, 0, stream>>>(x, lengths, Ax);
    scores_gemm_fast<<<dim3(8, 512), 256, 0, stream>>>(Ax, lengths, Bt, bias, key, scores);
  } else {
    conv_w_flat<<<dim3(8, 32), 256, 0, stream>>>(W, (unsigned short*)Bt);
    scores_gemm_split<<<dim3(8, 512), 256, 0, stream>>>(x, lengths, (unsigned short*)Bt,
                                                        bias, key, scores);
  }
  softmax_kernel<<<dim3(BB), 256, 0, stream>>>(scores, lengths);
  wsum_kernel<<<dim3(SS / SCH, BB), 256, 0, stream>>>(x, scores, lengths, out);
}

// Round 4
// 650.708 us; speedup vs baseline: 1.0672x; 1.0672x over previous
//
#include <hip/hip_runtime.h>
#include <math.h>

#define BB 16
#define SS 4096
#define HH 1024
#define SCH 64

// d_ws layout:
//   [0, 256 KB)              : scores / attn probs, B*S fp32 (atomicAdd target)
//   [256 KB, +4 MB)          : W hi/lo bf16, chunk-ordered [ct128(8)][kc(32)] x 16 KB
//   [+4 MB, +268 MB)         : x hi/lo bf16, chunk-ordered [b*32+rt][kc(32)] x 16 KB
// 16 KB chunk internal: [plane(2):8192][rowblk(4):2048][kh(2):1024], each 1 KB
//   = [khsel(2):512][row(32):16] -> LDS/global offset = base + lane*16 exactly.

typedef __attribute__((ext_vector_type(8))) short bf16x8;
typedef __attribute__((ext_vector_type(16))) float f32x16;

__device__ __forceinline__ void gl_lds16(const void* g, void* l) {
  __builtin_amdgcn_global_load_lds(
      (const __attribute__((address_space(1))) void*)g,
      (__attribute__((address_space(3))) void*)l, 16, 0, 0);
}

__device__ __forceinline__ void pack8(float4 a, float4 b, uint4& hp, uint4& lp) {
  float f[8] = {a.x, a.y, a.z, a.w, b.x, b.y, b.z, b.w};
  unsigned h[8], l[8];
#pragma unroll
  for (int i = 0; i < 8; ++i) {
    unsigned u = __float_as_uint(f[i]);
    h[i] = u >> 16;
    l[i] = __float_as_uint(f[i] - __uint_as_float(u & 0xffff0000u)) >> 16;
  }
  hp.x = h[0] | (h[1] << 16); hp.y = h[2] | (h[3] << 16);
  hp.z = h[4] | (h[5] << 16); hp.w = h[6] | (h[7] << 16);
  lp.x = l[0] | (l[1] << 16); lp.y = l[2] | (l[3] << 16);
  lp.z = l[4] | (l[5] << 16); lp.w = l[6] | (l[7] << 16);
}

// ---- W -> chunk-ordered hi/lo bf16 (unchanged layout, verified r2/r3) ------
__global__ __launch_bounds__(256) void conv_w_tiled(const float* __restrict__ W,
                                                    char* __restrict__ Bt) {
  int ct = blockIdx.x, kc = blockIdx.y;
  char* blk = Bt + (size_t)(ct * 32 + kc) * 16384;
  int tid = threadIdx.x;
#pragma unroll
  for (int i = 0; i < 2; ++i) {
    int oi = i * 256 + tid;
    int n = oi >> 2, koct = oi & 3;
    const float* src = W + (size_t)(ct * 128 + n) * HH + kc * 32 + koct * 8;
    float4 v0 = *(const float4*)src;
    float4 v1 = *(const float4*)(src + 4);
    uint4 hp, lp;
    pack8(v0, v1, hp, lp);
    int nb = n >> 5, nrow = n & 31, kh = koct >> 1, khs = koct & 1;
    int off = (((nb * 2 + kh) * 2 + khs) << 9) + nrow * 16;
    *(uint4*)(blk + off) = hp;
    *(uint4*)(blk + 8192 + off) = lp;
  }
}

// ---- x -> chunk-ordered hi/lo bf16; wave writes whole 1 KB blocks ---------
// grid (32 rt, 16 b, 2 kc-halves), 256 threads (4 waves).
__global__ __launch_bounds__(256) void conv_x_tiled(const float* __restrict__ x,
                                                    const int* __restrict__ lengths,
                                                    char* __restrict__ Ax) {
  int rt = blockIdx.x, b = blockIdx.y, kg = blockIdx.z;
  if (rt * 128 >= lengths[b]) return;
  int tid = threadIdx.x;
  int lane = tid & 63, w = tid >> 6;
  int mrow = lane & 31, khs = lane >> 5;
  const float* xb = x + ((size_t)b * SS + rt * 128) * HH;
  char* tile0 = Ax + (size_t)(b * 32 + rt) * (32 * 16384);
#pragma unroll 4
  for (int it = 0; it < 32; ++it) {
    int jj = w * 32 + it;            // contiguous per wave: kh fastest -> L1 reuse
    int kc = kg * 16 + (jj >> 3);
    int rb = (jj >> 1) & 3;
    int kh = jj & 1;
    int row = rb * 32 + mrow;
    const float* src = xb + (size_t)row * HH + kc * 32 + kh * 16 + khs * 8;
    float4 v0 = *(const float4*)src;
    float4 v1 = *(const float4*)(src + 4);
    uint4 hp, lp;
    pack8(v0, v1, hp, lp);
    char* blk = tile0 + kc * 16384 + rb * 2048 + kh * 1024;   // plane0
    *(uint4*)(blk + lane * 16) = hp;                          // contiguous 1 KB/wave
    *(uint4*)(blk + 8192 + lane * 16) = lp;                   // plane1
  }
}

// ---- scores GEMM: 256x256 tile, 8 waves, double-buffered LDS --------------
// grid (4 col-blocks, 256 row-tiles), 512 threads, dynamic LDS 128 KB.
__global__ __launch_bounds__(512, 2) void scores_gemm_256(
    const char* __restrict__ Ax, const int* __restrict__ lengths,
    const char* __restrict__ Bt, const float* __restrict__ bias,
    const float* __restrict__ key, float* __restrict__ scores) {
  int ctb = blockIdx.x;                 // cols ctb*256
  int t = blockIdx.y;
  int b = t >> 4, m256 = t & 15;
  int s0 = m256 * 256;
  if (s0 >= lengths[b]) return;

  extern __shared__ char lds[];         // 2 x 65536
  int tid = threadIdx.x;
  int lane = tid & 63, w = tid >> 6;
  int wm = w & 3, wn = w >> 2;          // wave tile: rows wm*64, cols wn*128

  f32x16 acc[2][4];
#pragma unroll
  for (int mt = 0; mt < 2; ++mt)
#pragma unroll
    for (int nt = 0; nt < 4; ++nt)
#pragma unroll
      for (int i = 0; i < 16; ++i) acc[mt][nt][i] = 0.f;

  // 8 staging pointers per thread (one 1 KB block per wave per call)
  const char* At0 = Ax + (size_t)(b * 32 + m256 * 2) * (32 * 16384);
  const char* At1 = At0 + 32 * 16384;
  const char* Bg0 = Bt + (size_t)(ctb * 2) * (32 * 16384);
  const char* Bg1 = Bg0 + 32 * 16384;
  const char* srcs[8];
  int dsto[8];
#pragma unroll
  for (int i = 0; i < 8; ++i) {
    int o = (i * 8 + w) * 1024;
    const char* base = (o < 16384) ? (At0 + o)
                     : (o < 32768) ? (At1 + (o - 16384))
                     : (o < 49152) ? (Bg0 + (o - 32768))
                                   : (Bg1 + (o - 49152));
    srcs[i] = base + lane * 16;
    dsto[i] = o;
  }

  // prologue: stage kc=0 into buf 0
#pragma unroll
  for (int i = 0; i < 8; ++i) {
    gl_lds16(srcs[i], lds + dsto[i]);
    srcs[i] += 16384;
  }
  __syncthreads();

  int buf = 0;
  for (int kc = 0; kc < 32; ++kc) {
    if (kc < 31) {                       // prefetch next kc into other buffer
      int nb = buf ^ 1;
#pragma unroll
      for (int i = 0; i < 8; ++i) {
        gl_lds16(srcs[i], lds + nb * 65536 + dsto[i]);
        srcs[i] += 16384;
      }
    }
    char* L = lds + buf * 65536;
    char* aB = L + (wm >> 1) * 16384 + (wm & 1) * 2 * 2048 + lane * 16;
    char* bB = L + 32768 + wn * 16384 + lane * 16;
#pragma unroll
    for (int kh = 0; kh < 2; ++kh) {
      bf16x8 ah[2], al[2], bh[4], bl[4];
#pragma unroll
      for (int mt = 0; mt < 2; ++mt) {
        ah[mt] = *(bf16x8*)(aB + mt * 2048 + kh * 1024);
        al[mt] = *(bf16x8*)(aB + 8192 + mt * 2048 + kh * 1024);
      }
#pragma unroll
      for (int nt = 0; nt < 4; ++nt) {
        bh[nt] = *(bf16x8*)(bB + nt * 2048 + kh * 1024);
        bl[nt] = *(bf16x8*)(bB + 8192 + nt * 2048 + kh * 1024);
      }
#pragma unroll
      for (int mt = 0; mt < 2; ++mt)
#pragma unroll
        for (int nt = 0; nt < 4; ++nt) {
          acc[mt][nt] = __builtin_amdgcn_mfma_f32_32x32x16_bf16(
              ah[mt], bh[nt], acc[mt][nt], 0, 0, 0);
          acc[mt][nt] = __builtin_amdgcn_mfma_f32_32x32x16_bf16(
              ah[mt], bl[nt], acc[mt][nt], 0, 0, 0);
          acc[mt][nt] = __builtin_amdgcn_mfma_f32_32x32x16_bf16(
              al[mt], bh[nt], acc[mt][nt], 0, 0, 0);
        }
    }
    __syncthreads();
    buf ^= 1;
  }

  // epilogue: scores[row] += sum_o tanh(pre + bias[o]) * key[o]
  // C/D map (32x32): col = lane&31, row = (reg&3) + 8*(reg>>2) + 4*(lane>>5)
  int col = lane & 31;
  int rbase = (lane >> 5) * 4;
  float bo[4], ko[4];
#pragma unroll
  for (int nt = 0; nt < 4; ++nt) {
    int o = ctb * 256 + wn * 128 + nt * 32 + col;
    bo[nt] = bias[o];
    ko[nt] = key[o];
  }
  float* srow = scores + (size_t)b * SS + s0;
#pragma unroll
  for (int mt = 0; mt < 2; ++mt) {
#pragma unroll
    for (int reg = 0; reg < 16; ++reg) {
      float sv = 0.f;
#pragma unroll
      for (int nt = 0; nt < 4; ++nt)
        sv += tanhf(acc[mt][nt][reg] + bo[nt]) * ko[nt];
#pragma unroll
      for (int off = 1; off < 32; off <<= 1) sv += __shfl_xor(sv, off);
      if (col == 0) {
        int row = wm * 64 + mt * 32 + (reg & 3) + 8 * (reg >> 2) + rbase;
        atomicAdd(srow + row, sv);
      }
    }
  }
}

// ---- masked softmax over s < L, in place -----------------------------------
__global__ __launch_bounds__(256) void softmax_kernel(float* __restrict__ sc,
                                                      const int* __restrict__ lengths) {
  int b = blockIdx.x;
  int L = lengths[b];
  float* p = sc + (size_t)b * SS;
  __shared__ float sred[34];
  int tid = threadIdx.x;

  float m = -3.0e38f;
  for (int s = tid; s < L; s += 256) m = fmaxf(m, p[s]);
  for (int off = 32; off > 0; off >>= 1) m = fmaxf(m, __shfl_down(m, off));
  if ((tid & 63) == 0) sred[tid >> 6] = m;
  __syncthreads();
  if (tid == 0) {
    float mm = sred[0];
    for (int w = 1; w < 4; ++w) mm = fmaxf(mm, sred[w]);
    sred[32] = mm;
  }
  __syncthreads();
  m = sred[32];

  float z = 0.f;
  for (int s = tid; s < L; s += 256) z += expf(p[s] - m);
  for (int off = 32; off > 0; off >>= 1) z += __shfl_down(z, off);
  if ((tid & 63) == 0) sred[tid >> 6] = z;
  __syncthreads();
  if (tid == 0) {
    float zz = 0.f;
    for (int w = 0; w < 4; ++w) zz += sred[w];
    sred[33] = zz;
  }
  __syncthreads();
  float inv = 1.f / sred[33];
  for (int s = tid; s < L; s += 256) p[s] = expf(p[s] - m) * inv;
}

// ---- out[b,h] = sum_{s<L} p[b,s] * x[b,s,h] --------------------------------
__global__ __launch_bounds__(256) void wsum_kernel(const float* __restrict__ x,
                                                   const float* __restrict__ p,
                                                   const int* __restrict__ lengths,
                                                   float* __restrict__ out) {
  int b = blockIdx.y;
  int L = lengths[b];
  int sbeg = blockIdx.x * SCH;
  if (sbeg >= L) return;
  int send = min(sbeg + SCH, L);
  int h = threadIdx.x * 4;
  const float* xb = x + (size_t)b * SS * HH;
  const float* pb = p + (size_t)b * SS;
  float4 acc = {0.f, 0.f, 0.f, 0.f};
#pragma unroll 4
  for (int s = sbeg; s < send; ++s) {
    float wgt = pb[s];
    float4 v = *(const float4*)(xb + (size_t)s * HH + h);
    acc.x = fmaf(wgt, v.x, acc.x);
    acc.y = fmaf(wgt, v.y, acc.y);
    acc.z = fmaf(wgt, v.z, acc.z);
    acc.w = fmaf(wgt, v.w, acc.w);
  }
  float* o = out + (size_t)b * HH + h;
  atomicAdd(o + 0, acc.x);
  atomicAdd(o + 1, acc.y);
  atomicAdd(o + 2, acc.z);
  atomicAdd(o + 3, acc.w);
}

extern "C" void kernel_launch(void* const* d_in, const int* in_sizes, int n_in,
                              void* d_out, int out_size, void* d_ws, size_t ws_size,
                              hipStream_t stream) {
  const float* x = (const float*)d_in[0];
  const int* lengths = (const int*)d_in[1];
  const float* W = (const float*)d_in[2];
  const float* bias = (const float*)d_in[3];
  const float* key = (const float*)d_in[4];
  float* out = (float*)d_out;

  float* scores = (float*)d_ws;                                   // 256 KB
  char* Bt = (char*)d_ws + 256 * 1024;                            // 4 MB
  char* Ax = Bt + (size_t)4 * 1024 * 1024;                        // 268 MB

  // allow 128 KB dynamic LDS for the GEMM (idempotent, capture-safe)
  hipFuncSetAttribute((const void*)scores_gemm_256,
                      hipFuncAttributeMaxDynamicSharedMemorySize, 131072);

  hipMemsetAsync(d_out, 0, (size_t)out_size * sizeof(float), stream);
  hipMemsetAsync(scores, 0, (size_t)BB * SS * sizeof(float), stream);

  conv_w_tiled<<<dim3(8, 32), 256, 0, stream>>>(W, Bt);
  conv_x_tiled<<<dim3(32, BB, 2), 256, 0, stream>>>(x, lengths, Ax);
  scores_gemm_256<<<dim3(4, 256), 512, 131072, stream>>>(Ax, lengths, Bt, bias, key, scores);
  softmax_kernel<<<dim3(BB), 256, 0, stream>>>(scores, lengths);
  wsum_kernel<<<dim3(SS / SCH, BB), 256, 0, stream>>>(x, scores, lengths, out);
}